// Round 4
// baseline (354.345 us; speedup 1.0000x reference)
//
#include <hip/hip_runtime.h>
#include <hip/hip_bf16.h>

typedef __attribute__((ext_vector_type(8))) short short8;
typedef __attribute__((ext_vector_type(8))) unsigned short ushort8;
typedef __attribute__((ext_vector_type(4))) float f32x4;
typedef unsigned short ushort;

#define K_DIM 4096
#define N_DIM 4096
#define BK 32
#define NT_TILES (K_DIM / BK)   // 128 K-tiles

// ---------- numerics helpers (exactly mirror the reference) ----------

__device__ __forceinline__ float e4m3_rne(float v) {
    if (v >= 0.015625f) {            // normal range: keep 3 mantissa bits, RNE
        unsigned u = __float_as_uint(v);
        unsigned lsb = (u >> 20) & 1u;
        u = (u + 0x7FFFFu + lsb) & 0xFFF00000u;
        return __uint_as_float(u);
    }
    return rintf(v * 512.0f) * 0.001953125f;   // subnormal: multiples of 2^-9
}

__device__ __forceinline__ float e2m1_level(float m) {
    float lv = 0.0f;
    lv = (m > 0.25f) ? 0.5f : lv;
    lv = (m > 0.75f) ? 1.0f : lv;
    lv = (m > 1.25f) ? 1.5f : lv;
    lv = (m > 1.75f) ? 2.0f : lv;
    lv = (m > 2.5f)  ? 3.0f : lv;
    lv = (m > 3.5f)  ? 4.0f : lv;
    lv = (m > 5.0f)  ? 6.0f : lv;
    return lv;
}

__device__ __forceinline__ ushort f32_to_bf16_bits(float f) {
    unsigned u = __float_as_uint(f);
    return (ushort)((u + 0x7FFFu + ((u >> 16) & 1u)) >> 16);
}

// ---------- small kernels ----------

__global__ void wamax_kernel(const float* __restrict__ w, unsigned* amax_bits, int n4) {
    float m = 0.f;
    const f32x4* w4 = (const f32x4*)w;
    for (int i = blockIdx.x * blockDim.x + threadIdx.x; i < n4; i += gridDim.x * blockDim.x) {
        f32x4 v = w4[i];   // normal (cached) load: quant_w re-reads w from LLC
        m = fmaxf(m, fmaxf(fmaxf(fabsf(v.x), fabsf(v.y)), fmaxf(fabsf(v.z), fabsf(v.w))));
    }
#pragma unroll
    for (int off = 32; off >= 1; off >>= 1)
        m = fmaxf(m, __shfl_down(m, off));
    __shared__ float red[4];
    const int lane = threadIdx.x & 63, wv = threadIdx.x >> 6;
    if (lane == 0) red[wv] = m;
    __syncthreads();
    if (threadIdx.x == 0) {
        m = fmaxf(fmaxf(red[0], red[1]), fmaxf(red[2], red[3]));
        atomicMax(amax_bits, __float_as_uint(m));
    }
}

// one thread = one 16-element block along K; non-temporal fp32 loads
// (single-use streams must not evict xq/wq from the LLC)
__global__ void quant16_kernel(const float* __restrict__ src,
                               const float* __restrict__ s2_ptr,
                               const unsigned* __restrict__ amax_bits,
                               ushort* __restrict__ dst, int nblk) {
    int t = blockIdx.x * blockDim.x + threadIdx.x;
    if (t >= nblk) return;
    float s2;
    if (s2_ptr) s2 = *s2_ptr;
    else        s2 = 2688.0f / __uint_as_float(*amax_bits);

    const f32x4* s = (const f32x4*)src + (size_t)t * 4;
    float vals[16];
    f32x4 v0 = __builtin_nontemporal_load(s + 0);
    f32x4 v1 = __builtin_nontemporal_load(s + 1);
    f32x4 v2 = __builtin_nontemporal_load(s + 2);
    f32x4 v3 = __builtin_nontemporal_load(s + 3);
#pragma unroll
    for (int i = 0; i < 4; ++i) {
        vals[i] = v0[i]; vals[4 + i] = v1[i]; vals[8 + i] = v2[i]; vals[12 + i] = v3[i];
    }
    float amax = 0.f;
#pragma unroll
    for (int i = 0; i < 16; ++i) amax = fmaxf(amax, fabsf(vals[i]));

    float sf = e4m3_rne(fminf(amax * s2 / 6.0f, 448.0f));
    float scale = sf / s2;

    ushort8 o0, o1;
    if (scale > 0.f) {
#pragma unroll
        for (int i = 0; i < 16; ++i) {
            float r = vals[i] / scale;
            float m = fminf(fabsf(r), 6.0f);
            float q = copysignf(e2m1_level(m), r);
            ushort b = f32_to_bf16_bits(q * scale);
            if (i < 8) o0[i] = b; else o1[i - 8] = b;
        }
    } else {
#pragma unroll
        for (int i = 0; i < 8; ++i) { o0[i] = 0; o1[i] = 0; }
    }
    ushort8* d8 = (ushort8*)(dst + (size_t)t * 16);
    d8[0] = o0;   // normal stores: xq/wq should LIVE in LLC for the GEMM
    d8[1] = o1;
}

// ---------- GEMM: C[M,N] = A[M,K]*B[N,K]^T + bias ----------
// 256x256 tile, BK=32, 8 waves (2M x 4N), 4-deep LDS ring, counted vmcnt.
// (R2 structure: proven 47.7% MfmaUtil, 0 bank conflicts.)

__device__ __forceinline__ void gload16(const ushort* g, ushort* l) {
    __builtin_amdgcn_global_load_lds(
        (const __attribute__((address_space(1))) void*)g,
        (__attribute__((address_space(3))) void*)l, 16, 0, 0);
}

#define SYNC(N)                                              \
    asm volatile("s_waitcnt vmcnt(" #N ")" ::: "memory");    \
    __builtin_amdgcn_sched_barrier(0);                       \
    __builtin_amdgcn_s_barrier();                            \
    __builtin_amdgcn_sched_barrier(0)

__global__ __launch_bounds__(512, 2) void gemm8(
    const ushort* __restrict__ Aq, const ushort* __restrict__ Bq,
    const float* __restrict__ bias, float* __restrict__ C,
    int nby, int nchunk) {
    // 4 ring buffers x (A 256x32 + B 256x32) bf16 = 4 x 32 KB = 128 KB
    __shared__ ushort lds[4 * 16384];

    const int tid  = threadIdx.x;
    const int lane = tid & 63;
    const int wave = tid >> 6;
    const int wr = wave >> 2;    // 0..1  (128-row half of A)
    const int wc = wave & 3;     // 0..3  (64-col group of B)

    // bijective XCD swizzle (nwg % 8 == 0), B-panel-major so each XCD keeps
    // 2 B-panels (4 MB) resident in its L2
    const int swz = (blockIdx.x & 7) * nchunk + (blockIdx.x >> 3);
    const int by = swz % nby, bx = swz / nby;
    const int bm = by * 256, bn = bx * 256;

    // ---- staging: LDS linear in tid order; global source pre-swizzled ----
    // slot p of row r holds k-group cg = (p - (r>>1)) & 3
    const int r0  = tid >> 2;
    const int cg0 = ((tid & 3) - ((r0 >> 1) & 3)) & 3;
    const ushort* sA0 = Aq + (size_t)(bm + r0) * K_DIM + cg0 * 8;
    const ushort* sB0 = Bq + (size_t)(bn + r0) * K_DIM + cg0 * 8;
    ushort* dA0 = &lds[wave * 512];           // + buf*16384 ; c=1 half at +4096
    ushort* dB0 = &lds[8192 + wave * 512];

    // ---- fragment read offsets (swizzled): p = (kgrp + (row>>1)) & 3 ----
    const int pr   = ((lane >> 4) + ((lane & 15) >> 1)) & 3;
    const int idxA = (wr * 128 + (lane & 15)) * 32 + pr * 8;
    const int idxB = 8192 + (wc * 64 + (lane & 15)) * 32 + pr * 8;

    f32x4 acc[8][4];
#pragma unroll
    for (int m = 0; m < 8; ++m)
#pragma unroll
        for (int n = 0; n < 4; ++n) acc[m][n] = (f32x4)(0.f);

#define STAGE(t) {                                                         \
        const size_t ko = (size_t)(t) * BK;                                \
        const int bb = ((t) & 3) * 16384;                                  \
        gload16(sA0 + ko,                          dA0 + bb);              \
        gload16(sA0 + (size_t)128 * K_DIM + ko,    dA0 + bb + 4096);       \
        gload16(sB0 + ko,                          dB0 + bb);              \
        gload16(sB0 + (size_t)128 * K_DIM + ko,    dB0 + bb + 4096); }

    auto compute = [&](int bufo) {
        const ushort* Lb = &lds[bufo];
        short8 af[8], bfr[4];
#pragma unroll
        for (int m = 0; m < 8; ++m) af[m]  = *(const short8*)(Lb + idxA + m * 512);
#pragma unroll
        for (int n = 0; n < 4; ++n) bfr[n] = *(const short8*)(Lb + idxB + n * 512);
#pragma unroll
        for (int m = 0; m < 8; ++m)
#pragma unroll
            for (int n = 0; n < 4; ++n)
                acc[m][n] = __builtin_amdgcn_mfma_f32_16x16x32_bf16(af[m], bfr[n], acc[m][n], 0, 0, 0);
    };

    // prologue: 3 tiles in flight
    STAGE(0); STAGE(1); STAGE(2);
    SYNC(8);                       // tile 0 landed (all waves), 8 loads in flight

    for (int t = 0; t < NT_TILES - 3; ++t) {
        STAGE(t + 3);              // slot (t+3)&3 free since end of tile t-1
        compute((t & 3) * 16384);
        SYNC(8);                   // tile t+1 landed; tiles t+2,t+3 in flight
    }
    compute(((NT_TILES - 3) & 3) * 16384);
    SYNC(4);                       // tile NT-2 landed
    compute(((NT_TILES - 2) & 3) * 16384);
    SYNC(0);                       // tile NT-1 landed
    compute(((NT_TILES - 1) & 3) * 16384);

    // ---- epilogue: C/D layout col=lane&15, row=(lane>>4)*4+reg ----
    // non-temporal C stores: 128 MB/dispatch must not flush xq/wq out of LLC
    const int fq = lane >> 4, fr = lane & 15;
    float bv[4];
#pragma unroll
    for (int n = 0; n < 4; ++n) bv[n] = bias[bn + wc * 64 + n * 16 + fr];
#pragma unroll
    for (int m = 0; m < 8; ++m)
#pragma unroll
        for (int r = 0; r < 4; ++r) {
            const int row = bm + wr * 128 + m * 16 + fq * 4 + r;
            float* Cr = C + (size_t)row * N_DIM + bn + wc * 64 + fr;
#pragma unroll
            for (int n = 0; n < 4; ++n)
                __builtin_nontemporal_store(acc[m][n][r] + bv[n], &Cr[n * 16]);
        }
#undef STAGE
}

// ---------- launcher ----------

extern "C" void kernel_launch(void* const* d_in, const int* in_sizes, int n_in,
                              void* d_out, int out_size, void* d_ws, size_t ws_size,
                              hipStream_t stream) {
    const float* x     = (const float*)d_in[0];
    const float* w     = (const float*)d_in[1];
    const float* bias  = (const float*)d_in[2];
    const float* s_in2 = (const float*)d_in[3];
    float* out = (float*)d_out;

    const int M = in_sizes[0] / K_DIM;   // 8192

    unsigned* amax_bits = (unsigned*)d_ws;
    ushort* xq = (ushort*)((char*)d_ws + 256);
    ushort* wq = (ushort*)((char*)d_ws + 256 + (size_t)M * K_DIM * 2);

    hipMemsetAsync(amax_bits, 0, 4, stream);
    wamax_kernel<<<1024, 256, 0, stream>>>(w, amax_bits, (N_DIM * K_DIM) / 4);

    const int nblk_x = (M * K_DIM) / 16;
    quant16_kernel<<<nblk_x / 256, 256, 0, stream>>>(x, s_in2, nullptr, xq, nblk_x);
    const int nblk_w = (N_DIM * K_DIM) / 16;
    quant16_kernel<<<nblk_w / 256, 256, 0, stream>>>(w, nullptr, amax_bits, wq, nblk_w);

    const int nby = M / 256;                 // 32
    const int nwg = nby * (N_DIM / 256);     // 512
    gemm8<<<nwg, 512, 0, stream>>>(xq, wq, bias, out, nby, nwg / 8);
}

// Round 5
// 310.070 us; speedup vs baseline: 1.1428x; 1.1428x over previous
//
#include <hip/hip_runtime.h>
#include <hip/hip_bf16.h>

typedef __attribute__((ext_vector_type(8))) short short8;
typedef __attribute__((ext_vector_type(8))) unsigned short ushort8;
typedef __attribute__((ext_vector_type(4))) float f32x4;
typedef unsigned short ushort;

#define K_DIM 4096
#define N_DIM 4096
#define BK 32
#define NT_TILES (K_DIM / BK)   // 128 K-tiles

// ---------- numerics helpers (exactly mirror the reference) ----------

__device__ __forceinline__ float e4m3_rne(float v) {
    if (v >= 0.015625f) {            // normal range: keep 3 mantissa bits, RNE
        unsigned u = __float_as_uint(v);
        unsigned lsb = (u >> 20) & 1u;
        u = (u + 0x7FFFFu + lsb) & 0xFFF00000u;
        return __uint_as_float(u);
    }
    return rintf(v * 512.0f) * 0.001953125f;   // subnormal: multiples of 2^-9
}

__device__ __forceinline__ float e2m1_level(float m) {
    float lv = 0.0f;
    lv = (m > 0.25f) ? 0.5f : lv;
    lv = (m > 0.75f) ? 1.0f : lv;
    lv = (m > 1.25f) ? 1.5f : lv;
    lv = (m > 1.75f) ? 2.0f : lv;
    lv = (m > 2.5f)  ? 3.0f : lv;
    lv = (m > 3.5f)  ? 4.0f : lv;
    lv = (m > 5.0f)  ? 6.0f : lv;
    return lv;
}

__device__ __forceinline__ ushort f32_to_bf16_bits(float f) {
    unsigned u = __float_as_uint(f);
    return (ushort)((u + 0x7FFFu + ((u >> 16) & 1u)) >> 16);
}

// ---------- small kernels ----------

__global__ void wamax_kernel(const float* __restrict__ w, unsigned* amax_bits, int n4) {
    float m = 0.f;
    const f32x4* w4 = (const f32x4*)w;
    for (int i = blockIdx.x * blockDim.x + threadIdx.x; i < n4; i += gridDim.x * blockDim.x) {
        f32x4 v = w4[i];
        m = fmaxf(m, fmaxf(fmaxf(fabsf(v.x), fabsf(v.y)), fmaxf(fabsf(v.z), fabsf(v.w))));
    }
#pragma unroll
    for (int off = 32; off >= 1; off >>= 1)
        m = fmaxf(m, __shfl_down(m, off));
    __shared__ float red[4];
    const int lane = threadIdx.x & 63, wv = threadIdx.x >> 6;
    if (lane == 0) red[wv] = m;
    __syncthreads();
    if (threadIdx.x == 0) {
        m = fmaxf(fmaxf(red[0], red[1]), fmaxf(red[2], red[3]));
        atomicMax(amax_bits, __float_as_uint(m));
    }
}

__global__ void quant16_kernel(const float* __restrict__ src,
                               const float* __restrict__ s2_ptr,
                               const unsigned* __restrict__ amax_bits,
                               ushort* __restrict__ dst, int nblk) {
    int t = blockIdx.x * blockDim.x + threadIdx.x;
    if (t >= nblk) return;
    float s2;
    if (s2_ptr) s2 = *s2_ptr;
    else        s2 = 2688.0f / __uint_as_float(*amax_bits);

    const f32x4* s = (const f32x4*)src + (size_t)t * 4;
    float vals[16];
    f32x4 v0 = s[0], v1 = s[1], v2 = s[2], v3 = s[3];
#pragma unroll
    for (int i = 0; i < 4; ++i) {
        vals[i] = v0[i]; vals[4 + i] = v1[i]; vals[8 + i] = v2[i]; vals[12 + i] = v3[i];
    }
    float amax = 0.f;
#pragma unroll
    for (int i = 0; i < 16; ++i) amax = fmaxf(amax, fabsf(vals[i]));

    float sf = e4m3_rne(fminf(amax * s2 / 6.0f, 448.0f));
    float scale = sf / s2;

    ushort8 o0, o1;
    if (scale > 0.f) {
#pragma unroll
        for (int i = 0; i < 16; ++i) {
            float r = vals[i] / scale;
            float m = fminf(fabsf(r), 6.0f);
            float q = copysignf(e2m1_level(m), r);
            ushort b = f32_to_bf16_bits(q * scale);
            if (i < 8) o0[i] = b; else o1[i - 8] = b;
        }
    } else {
#pragma unroll
        for (int i = 0; i < 8; ++i) { o0[i] = 0; o1[i] = 0; }
    }
    ushort8* d8 = (ushort8*)(dst + (size_t)t * 16);
    d8[0] = o0;
    d8[1] = o1;
}

// ---------- GEMM: C[M,N] = A[M,K]*B[N,K]^T + bias ----------
// 256x256 tile, BK=32, 8 waves (2M x 4N), 4-deep LDS ring, counted vmcnt.
// R2 schedule (proven 47.7% MfmaUtil, 0 bank conflicts) + supertile swizzle:
// first 256 blocks cover a 16x16 tile region -> 64 MB live operand set (fits L3).

__device__ __forceinline__ void gload16(const ushort* g, ushort* l) {
    __builtin_amdgcn_global_load_lds(
        (const __attribute__((address_space(1))) void*)g,
        (__attribute__((address_space(3))) void*)l, 16, 0, 0);
}

#define SYNC(N)                                              \
    asm volatile("s_waitcnt vmcnt(" #N ")" ::: "memory");    \
    __builtin_amdgcn_sched_barrier(0);                       \
    __builtin_amdgcn_s_barrier();                            \
    __builtin_amdgcn_sched_barrier(0)

__global__ __launch_bounds__(512, 2) void gemm8(
    const ushort* __restrict__ Aq, const ushort* __restrict__ Bq,
    const float* __restrict__ bias, float* __restrict__ C) {
    // 4 ring buffers x (A 256x32 + B 256x32) bf16 = 4 x 32 KB = 128 KB
    __shared__ ushort lds[4 * 16384];

    const int tid  = threadIdx.x;
    const int lane = tid & 63;
    const int wave = tid >> 6;
    const int wr = wave >> 2;    // 0..1  (128-row half of A)
    const int wc = wave & 3;     // 0..3  (64-col group of B)

    // supertile swizzle: group g = 256 ranks = 16(by) x 16(bx) compact region
    const int swz = blockIdx.x;
    const int g = swz >> 8, l = swz & 255;
    const int by = g * 16 + (l & 15);
    const int bx = l >> 4;
    const int bm = by * 256, bn = bx * 256;

    // ---- staging: LDS linear in tid order; global source pre-swizzled ----
    // slot p of row r holds k-group cg = (p - (r>>1)) & 3
    const int r0  = tid >> 2;
    const int cg0 = ((tid & 3) - ((r0 >> 1) & 3)) & 3;
    const ushort* sA0 = Aq + (size_t)(bm + r0) * K_DIM + cg0 * 8;
    const ushort* sB0 = Bq + (size_t)(bn + r0) * K_DIM + cg0 * 8;
    ushort* dA0 = &lds[wave * 512];           // + buf*16384 ; c=1 half at +4096
    ushort* dB0 = &lds[8192 + wave * 512];

    // ---- fragment read offsets (swizzled): p = (kgrp + (row>>1)) & 3 ----
    const int pr   = ((lane >> 4) + ((lane & 15) >> 1)) & 3;
    const int idxA = (wr * 128 + (lane & 15)) * 32 + pr * 8;
    const int idxB = 8192 + (wc * 64 + (lane & 15)) * 32 + pr * 8;

    f32x4 acc[8][4];
#pragma unroll
    for (int m = 0; m < 8; ++m)
#pragma unroll
        for (int n = 0; n < 4; ++n) acc[m][n] = (f32x4)(0.f);

#define STAGE(t) {                                                         \
        const size_t ko = (size_t)(t) * BK;                                \
        const int bb = ((t) & 3) * 16384;                                  \
        gload16(sA0 + ko,                          dA0 + bb);              \
        gload16(sA0 + (size_t)128 * K_DIM + ko,    dA0 + bb + 4096);       \
        gload16(sB0 + ko,                          dB0 + bb);              \
        gload16(sB0 + (size_t)128 * K_DIM + ko,    dB0 + bb + 4096); }

    auto compute = [&](int bufo) {
        const ushort* Lb = &lds[bufo];
        short8 af[8], bfr[4];
#pragma unroll
        for (int m = 0; m < 8; ++m) af[m]  = *(const short8*)(Lb + idxA + m * 512);
#pragma unroll
        for (int n = 0; n < 4; ++n) bfr[n] = *(const short8*)(Lb + idxB + n * 512);
#pragma unroll
        for (int m = 0; m < 8; ++m)
#pragma unroll
            for (int n = 0; n < 4; ++n)
                acc[m][n] = __builtin_amdgcn_mfma_f32_16x16x32_bf16(af[m], bfr[n], acc[m][n], 0, 0, 0);
    };

    // prologue: 3 tiles in flight
    STAGE(0); STAGE(1); STAGE(2);
    SYNC(8);                       // tile 0 landed (all waves), 8 loads in flight

    for (int t = 0; t < NT_TILES - 3; ++t) {
        STAGE(t + 3);              // slot (t+3)&3 free since end of tile t-1
        compute((t & 3) * 16384);
        SYNC(8);                   // tile t+1 landed; tiles t+2,t+3 in flight
    }
    compute(((NT_TILES - 3) & 3) * 16384);
    SYNC(4);                       // tile NT-2 landed
    compute(((NT_TILES - 2) & 3) * 16384);
    SYNC(0);                       // tile NT-1 landed
    compute(((NT_TILES - 1) & 3) * 16384);

    // ---- epilogue: C/D layout col=lane&15, row=(lane>>4)*4+reg ----
    const int fq = lane >> 4, fr = lane & 15;
    float bv[4];
#pragma unroll
    for (int n = 0; n < 4; ++n) bv[n] = bias[bn + wc * 64 + n * 16 + fr];
#pragma unroll
    for (int m = 0; m < 8; ++m)
#pragma unroll
        for (int r = 0; r < 4; ++r) {
            const int row = bm + wr * 128 + m * 16 + fq * 4 + r;
            float* Cr = C + (size_t)row * N_DIM + bn + wc * 64 + fr;
#pragma unroll
            for (int n = 0; n < 4; ++n) Cr[n * 16] = acc[m][n][r] + bv[n];
        }
#undef STAGE
}

// ---------- launcher ----------

extern "C" void kernel_launch(void* const* d_in, const int* in_sizes, int n_in,
                              void* d_out, int out_size, void* d_ws, size_t ws_size,
                              hipStream_t stream) {
    const float* x     = (const float*)d_in[0];
    const float* w     = (const float*)d_in[1];
    const float* bias  = (const float*)d_in[2];
    const float* s_in2 = (const float*)d_in[3];
    float* out = (float*)d_out;

    const int M = in_sizes[0] / K_DIM;   // 8192

    unsigned* amax_bits = (unsigned*)d_ws;
    ushort* xq = (ushort*)((char*)d_ws + 256);
    ushort* wq = (ushort*)((char*)d_ws + 256 + (size_t)M * K_DIM * 2);

    hipMemsetAsync(amax_bits, 0, 4, stream);
    wamax_kernel<<<1024, 256, 0, stream>>>(w, amax_bits, (N_DIM * K_DIM) / 4);

    const int nblk_x = (M * K_DIM) / 16;
    quant16_kernel<<<nblk_x / 256, 256, 0, stream>>>(x, s_in2, nullptr, xq, nblk_x);
    const int nblk_w = (N_DIM * K_DIM) / 16;
    quant16_kernel<<<nblk_w / 256, 256, 0, stream>>>(w, nullptr, amax_bits, wq, nblk_w);

    const int nwg = (M / 256) * (N_DIM / 256);   // 512
    gemm8<<<nwg, 512, 0, stream>>>(xq, wq, bias, out);
}